// Round 1
// baseline (234.349 us; speedup 1.0000x reference)
//
#include <hip/hip_runtime.h>
#include <stdint.h>

// Problem constants: B=2, S=2048, D=1024, H=16, DH=64
#define SB 2
#define SS 2048
#define SD 1024
#define SH 16
#define SDH 64
#define SM (SB*SS)          // 4096 rows
#define NEGINF_MASK -1000000000.0f
#define LOG2E 1.44269504088896340736f

typedef __attribute__((ext_vector_type(8))) short short8;
typedef __attribute__((ext_vector_type(4))) short short4v;
typedef __attribute__((ext_vector_type(4))) float f32x4;
typedef __attribute__((ext_vector_type(4))) float float4v;

__device__ static inline short f2bf(float f) {
    uint32_t u = __float_as_uint(f);
    u += 0x7fffu + ((u >> 16) & 1u);   // RNE
    return (short)(u >> 16);
}

__device__ static inline void gload_lds16(const void* g, void* l) {
    __builtin_amdgcn_global_load_lds(
        (__attribute__((address_space(1))) void*)g,
        (__attribute__((address_space(3))) void*)l,
        16, 0, 0);
}

// ---------------- fp32 -> bf16 convert (vectorized) ----------------
__global__ void cvt_bf16_kernel(const float* __restrict__ in, short* __restrict__ out, int n4) {
    int i = blockIdx.x * 256 + threadIdx.x;
    if (i < n4) {
        float4v v = *(const float4v*)(in + (size_t)i * 4);
        short4v o;
        o[0] = f2bf(v[0]); o[1] = f2bf(v[1]); o[2] = f2bf(v[2]); o[3] = f2bf(v[3]);
        *(short4v*)(out + (size_t)i * 4) = o;
    }
}

// ---------------- mask [B,S,S] int32 -> bit-packed u64 ----------------
__global__ void pack_mask_kernel(const int* __restrict__ mask, unsigned long long* __restrict__ bits) {
    unsigned int i = blockIdx.x * 256u + threadIdx.x;   // over B*S*S = 8388608
    int pred = mask[i] != 0;
    unsigned long long b = __ballot(pred);
    if ((threadIdx.x & 63u) == 0u) bits[i >> 6] = b;
}

// ---------------- GEMM: C[M,N] = A[M,K] * W[N,K]^T + bias, m97 structure ----------------
// 128x128 tile, BK=32, 4 waves (2x2), each wave 64x64 = 4x4 frags of 16x16x32 bf16 MFMA.
template <typename OutT>
__device__ inline void gemm_bt_body(const short* __restrict__ A, const short* __restrict__ W,
                                    const float* __restrict__ bias, OutT* __restrict__ C,
                                    int M, int N, int K, int rowBase, int colBase) {
    __shared__ short As[128 * 32];
    __shared__ short Bs[128 * 32];
    const int tid = threadIdx.x, lane = tid & 63, wid = tid >> 6;
    const int r15 = lane & 15, hi = lane >> 4;
    const int wr = wid >> 1, wc = wid & 1;

    f32x4 acc[4][4] = {};

    for (int kt = 0; kt < K; kt += 32) {
        // stage A tile [128][32] and W tile [128][32]; 512 chunks of 16B each, 2 per thread
#pragma unroll
        for (int c = 0; c < 2; ++c) {
            int chBase = c * 256 + wid * 64;     // wave-uniform LDS base (lane*16 added by HW)
            int ch = chBase + lane;
            gload_lds16(A + (size_t)(rowBase + (ch >> 2)) * K + kt + (ch & 3) * 8, &As[chBase * 8]);
        }
#pragma unroll
        for (int c = 0; c < 2; ++c) {
            int chBase = c * 256 + wid * 64;
            int ch = chBase + lane;
            gload_lds16(W + (size_t)(colBase + (ch >> 2)) * K + kt + (ch & 3) * 8, &Bs[chBase * 8]);
        }
        __syncthreads();   // drains vmcnt + barrier

        short8 aF[4], bF[4];
#pragma unroll
        for (int mi = 0; mi < 4; ++mi)
            aF[mi] = *(const short8*)&As[(wr * 64 + mi * 16 + r15) * 32 + hi * 8];
#pragma unroll
        for (int ni = 0; ni < 4; ++ni)
            bF[ni] = *(const short8*)&Bs[(wc * 64 + ni * 16 + r15) * 32 + hi * 8];
#pragma unroll
        for (int mi = 0; mi < 4; ++mi)
#pragma unroll
            for (int ni = 0; ni < 4; ++ni)
                acc[mi][ni] = __builtin_amdgcn_mfma_f32_16x16x32_bf16(aF[mi], bF[ni], acc[mi][ni], 0, 0, 0);
        __syncthreads();
    }

    // epilogue: D layout col=lane&15, row=(lane>>4)*4+reg
#pragma unroll
    for (int ni = 0; ni < 4; ++ni) {
        int col = colBase + wc * 64 + ni * 16 + r15;
        float bv = bias[col];
#pragma unroll
        for (int mi = 0; mi < 4; ++mi) {
#pragma unroll
            for (int r = 0; r < 4; ++r) {
                int row = rowBase + wr * 64 + mi * 16 + hi * 4 + r;
                float v = acc[mi][ni][r] + bv;
                if constexpr (sizeof(OutT) == 2) C[(size_t)row * N + col] = f2bf(v);
                else                             C[(size_t)row * N + col] = v;
            }
        }
    }
}

// QKV fused: blockIdx.z selects {Wq,Wk,Wv}
__global__ __launch_bounds__(256, 2) void gemm_qkv_kernel(
    const short* __restrict__ A,
    const short* __restrict__ W0, const short* __restrict__ W1, const short* __restrict__ W2,
    const float* __restrict__ b0, const float* __restrict__ b1, const float* __restrict__ b2,
    short* __restrict__ O0, short* __restrict__ O1, short* __restrict__ O2) {
    const short* W = (blockIdx.z == 0) ? W0 : (blockIdx.z == 1) ? W1 : W2;
    const float* bias = (blockIdx.z == 0) ? b0 : (blockIdx.z == 1) ? b1 : b2;
    short* C = (blockIdx.z == 0) ? O0 : (blockIdx.z == 1) ? O1 : O2;
    gemm_bt_body<short>(A, W, bias, C, SM, SD, SD, blockIdx.y * 128, blockIdx.x * 128);
}

// Output projection: fp32 out
__global__ __launch_bounds__(256, 2) void gemm_out_kernel(
    const short* __restrict__ A, const short* __restrict__ W,
    const float* __restrict__ bias, float* __restrict__ C) {
    gemm_bt_body<float>(A, W, bias, C, SM, SD, SD, blockIdx.y * 128, blockIdx.x * 128);
}

// ---------------- flash attention ----------------
// grid: (S/128, H, B); block 256 = 4 waves; wave owns 32 q rows; KV tile = 64.
__global__ __launch_bounds__(256, 2) void attn_kernel(
    const short* __restrict__ Q, const short* __restrict__ K, const short* __restrict__ V,
    const unsigned long long* __restrict__ mbits, short* __restrict__ O) {
    const int tid = threadIdx.x, lane = tid & 63, wid = tid >> 6;
    const int r15 = lane & 15, hi = lane >> 4;
    const int b = blockIdx.z, h = blockIdx.y;
    const int q0 = blockIdx.x * 128 + wid * 32;   // wave's first q row (within S)
    const int brow = b * SS;

    __shared__ short Ks[64 * 64];        // XOR-swizzled within 128B rows
    __shared__ short Vt[64 * 72];        // [dh][72] transposed V, +8 pad (144B rows, 16B aligned)
    __shared__ short Pl[4][32 * 72];     // per-wave P round-trip, +8 pad
    short* pw = Pl[wid];

    // Q fragments live in registers for all tiles
    short8 qF[2][2];
#pragma unroll
    for (int qf = 0; qf < 2; ++qf)
#pragma unroll
        for (int kd = 0; kd < 2; ++kd)
            qF[qf][kd] = *(const short8*)&Q[(size_t)(brow + q0 + qf * 16 + r15) * SD + h * SDH + kd * 32 + hi * 8];

    f32x4 o[2][4] = {};
    float mrun[2][4], lrun[2][4];
#pragma unroll
    for (int qf = 0; qf < 2; ++qf)
#pragma unroll
        for (int r = 0; r < 4; ++r) { mrun[qf][r] = -1e30f; lrun[qf][r] = 0.f; }

    for (int kt = 0; kt < SS; kt += 64) {
        // ---- stage K tile [64][64], source-swizzled so linear LDS holds swizzled layout ----
#pragma unroll
        for (int c = 0; c < 2; ++c) {
            int chBase = c * 256 + wid * 64;
            int ch = chBase + lane;             // 0..511
            int row = ch >> 3, c16 = ch & 7;
            gload_lds16(K + (size_t)(brow + kt + row) * SD + h * SDH + ((c16 ^ (row & 7)) * 8),
                        &Ks[chBase * 8]);
        }
        // ---- stage V transposed: thread -> row-pair p=tid&31, col chunk c0=(tid>>5)*8 ----
        {
            int p = tid & 31, c0 = (tid >> 5) * 8;
            const short* vs = V + (size_t)(brow + kt + 2 * p) * SD + h * SDH + c0;
            short8 va = *(const short8*)vs;
            short8 vb = *(const short8*)(vs + SD);
#pragma unroll
            for (int j = 0; j < 8; ++j) {
                uint32_t pk = (uint32_t)(uint16_t)va[j] | ((uint32_t)(uint16_t)vb[j] << 16);
                *(uint32_t*)&Vt[(c0 + j) * 72 + 2 * p] = pk;   // Vt[dh][k], k=2p even -> 4B aligned
            }
        }
        // mask bits: lanes 0..31 hold their q-row's 64 bits for this tile
        unsigned long long mb = 0;
        if (lane < 32) mb = mbits[(size_t)(brow + q0 + lane) * (SS / 64) + (kt >> 6)];
        __syncthreads();

        // ---- QK^T: s[qf][kc], D row=q(hi*4+r), col=k(kc*16+r15) ----
        f32x4 s[2][4] = {};
#pragma unroll
        for (int kc = 0; kc < 4; ++kc) {
            int krow = kc * 16 + r15;
#pragma unroll
            for (int kd = 0; kd < 2; ++kd) {
                short8 kF = *(const short8*)&Ks[krow * 64 + (((kd * 4 + hi) ^ (krow & 7)) * 8)];
                s[0][kc] = __builtin_amdgcn_mfma_f32_16x16x32_bf16(qF[0][kd], kF, s[0][kc], 0, 0, 0);
                s[1][kc] = __builtin_amdgcn_mfma_f32_16x16x32_bf16(qF[1][kd], kF, s[1][kc], 0, 0, 0);
            }
        }

        // ---- scale + mask + online softmax ----
#pragma unroll
        for (int qf = 0; qf < 2; ++qf) {
#pragma unroll
            for (int r = 0; r < 4; ++r) {
                unsigned long long mrow = __shfl(mb, qf * 16 + hi * 4 + r);
                float mx = -1e30f;
#pragma unroll
                for (int kc = 0; kc < 4; ++kc) {
                    float v = s[qf][kc][r] * 0.125f;
                    v = ((mrow >> (kc * 16 + r15)) & 1ull) ? v : NEGINF_MASK;
                    s[qf][kc][r] = v;
                    mx = fmaxf(mx, v);
                }
                mx = fmaxf(mx, __shfl_xor(mx, 1));
                mx = fmaxf(mx, __shfl_xor(mx, 2));
                mx = fmaxf(mx, __shfl_xor(mx, 4));
                mx = fmaxf(mx, __shfl_xor(mx, 8));
                float nm = fmaxf(mrun[qf][r], mx);
                float corr = exp2f((mrun[qf][r] - nm) * LOG2E);
                mrun[qf][r] = nm;
                float rs = 0.f;
#pragma unroll
                for (int kc = 0; kc < 4; ++kc) {
                    float p = exp2f((s[qf][kc][r] - nm) * LOG2E);
                    s[qf][kc][r] = p;
                    rs += p;
                }
                rs += __shfl_xor(rs, 1); rs += __shfl_xor(rs, 2);
                rs += __shfl_xor(rs, 4); rs += __shfl_xor(rs, 8);
                lrun[qf][r] = lrun[qf][r] * corr + rs;
#pragma unroll
                for (int df = 0; df < 4; ++df) o[qf][df][r] *= corr;
            }
        }

        // ---- P: D-layout -> LDS -> A-layout (wave-private; DS pipe is in-order per wave) ----
#pragma unroll
        for (int qf = 0; qf < 2; ++qf)
#pragma unroll
            for (int kc = 0; kc < 4; ++kc)
#pragma unroll
                for (int r = 0; r < 4; ++r)
                    pw[(qf * 16 + hi * 4 + r) * 72 + kc * 16 + r15] = f2bf(s[qf][kc][r]);

        short8 pF[2][2];
#pragma unroll
        for (int qf = 0; qf < 2; ++qf)
#pragma unroll
            for (int kf = 0; kf < 2; ++kf)
                pF[qf][kf] = *(const short8*)&pw[(qf * 16 + r15) * 72 + kf * 32 + hi * 8];

        // ---- PV: o[qf][df] += P * V ----
#pragma unroll
        for (int df = 0; df < 4; ++df) {
#pragma unroll
            for (int kf = 0; kf < 2; ++kf) {
                short8 vF = *(const short8*)&Vt[(df * 16 + r15) * 72 + kf * 32 + hi * 8];
                o[0][df] = __builtin_amdgcn_mfma_f32_16x16x32_bf16(pF[0][kf], vF, o[0][df], 0, 0, 0);
                o[1][df] = __builtin_amdgcn_mfma_f32_16x16x32_bf16(pF[1][kf], vF, o[1][df], 0, 0, 0);
            }
        }
        __syncthreads();   // protect Ks/Vt before next stage
    }

    // ---- epilogue: O = o / l, bf16 out at [b*S+q][h*64+dh] ----
#pragma unroll
    for (int qf = 0; qf < 2; ++qf)
#pragma unroll
        for (int r = 0; r < 4; ++r) {
            float inv = 1.0f / lrun[qf][r];
            size_t row = (size_t)(brow + q0 + qf * 16 + hi * 4 + r);
#pragma unroll
            for (int df = 0; df < 4; ++df)
                O[row * SD + h * SDH + df * 16 + r15] = f2bf(o[qf][df][r] * inv);
        }
}

// ---------------- host launcher ----------------
extern "C" void kernel_launch(void* const* d_in, const int* in_sizes, int n_in,
                              void* d_out, int out_size, void* d_ws, size_t ws_size,
                              hipStream_t stream) {
    const float* x  = (const float*)d_in[0];
    const int* mask = (const int*)d_in[1];
    const float* Wq = (const float*)d_in[2];
    const float* bq = (const float*)d_in[3];
    const float* Wk = (const float*)d_in[4];
    const float* bk = (const float*)d_in[5];
    const float* Wv = (const float*)d_in[6];
    const float* bv = (const float*)d_in[7];
    const float* Wo = (const float*)d_in[8];
    const float* bo = (const float*)d_in[9];
    float* out = (float*)d_out;

    char* ws = (char*)d_ws;
    size_t off = 0;
    auto alloc = [&](size_t bytes) { void* p = ws + off; off += (bytes + 255) & ~(size_t)255; return p; };

    short* xb  = (short*)alloc((size_t)SM * SD * 2);
    short* wqb = (short*)alloc((size_t)SD * SD * 2);
    short* wkb = (short*)alloc((size_t)SD * SD * 2);
    short* wvb = (short*)alloc((size_t)SD * SD * 2);
    short* wob = (short*)alloc((size_t)SD * SD * 2);
    short* Qb  = (short*)alloc((size_t)SM * SD * 2);
    short* Kb  = (short*)alloc((size_t)SM * SD * 2);
    short* Vb  = (short*)alloc((size_t)SM * SD * 2);
    short* AOb = (short*)alloc((size_t)SM * SD * 2);
    unsigned long long* mbits = (unsigned long long*)alloc((size_t)SB * SS * (SS / 64) * 8);

    cvt_bf16_kernel<<<(SM * SD / 4 + 255) / 256, 256, 0, stream>>>(x, xb, SM * SD / 4);
    cvt_bf16_kernel<<<(SD * SD / 4 + 255) / 256, 256, 0, stream>>>(Wq, wqb, SD * SD / 4);
    cvt_bf16_kernel<<<(SD * SD / 4 + 255) / 256, 256, 0, stream>>>(Wk, wkb, SD * SD / 4);
    cvt_bf16_kernel<<<(SD * SD / 4 + 255) / 256, 256, 0, stream>>>(Wv, wvb, SD * SD / 4);
    cvt_bf16_kernel<<<(SD * SD / 4 + 255) / 256, 256, 0, stream>>>(Wo, wob, SD * SD / 4);
    pack_mask_kernel<<<SB * SS * SS / 256, 256, 0, stream>>>(mask, mbits);

    gemm_qkv_kernel<<<dim3(SD / 128, SM / 128, 3), 256, 0, stream>>>(
        xb, wqb, wkb, wvb, bq, bk, bv, Qb, Kb, Vb);

    attn_kernel<<<dim3(SS / 128, SH, SB), 256, 0, stream>>>(Qb, Kb, Vb, mbits, AOb);

    gemm_out_kernel<<<dim3(SD / 128, SM / 128), 256, 0, stream>>>(AOb, wob, bo, out);
}

// Round 2
// 228.886 us; speedup vs baseline: 1.0239x; 1.0239x over previous
//
#include <hip/hip_runtime.h>
#include <stdint.h>

// Problem constants: B=2, S=2048, D=1024, H=16, DH=64
#define SB 2
#define SS 2048
#define SD 1024
#define SH 16
#define SDH 64
#define SM (SB*SS)          // 4096 rows
#define NEGINF_MASK -1000000000.0f
// Q pre-scale: (1/sqrt(DH)) * log2(e) = 0.125 * 1.4426950408889634
#define QSCALE 0.18033688011112043f

typedef __attribute__((ext_vector_type(8))) short short8;
typedef __attribute__((ext_vector_type(4))) short short4v;
typedef __attribute__((ext_vector_type(4))) float f32x4;
typedef __attribute__((ext_vector_type(4))) float float4v;

__device__ static inline short f2bf(float f) {
    uint32_t u = __float_as_uint(f);
    u += 0x7fffu + ((u >> 16) & 1u);   // RNE
    return (short)(u >> 16);
}

__device__ static inline void gload_lds16(const void* g, void* l) {
    __builtin_amdgcn_global_load_lds(
        (__attribute__((address_space(1))) void*)g,
        (__attribute__((address_space(3))) void*)l,
        16, 0, 0);
}

// ---------------- fp32 -> bf16 convert (vectorized) ----------------
__global__ void cvt_bf16_kernel(const float* __restrict__ in, short* __restrict__ out, int n4) {
    int i = blockIdx.x * 256 + threadIdx.x;
    if (i < n4) {
        float4v v = *(const float4v*)(in + (size_t)i * 4);
        short4v o;
        o[0] = f2bf(v[0]); o[1] = f2bf(v[1]); o[2] = f2bf(v[2]); o[3] = f2bf(v[3]);
        *(short4v*)(out + (size_t)i * 4) = o;
    }
}

// ---------------- mask [B,S,S] int32 -> bit-packed u64 ----------------
__global__ void pack_mask_kernel(const int* __restrict__ mask, unsigned long long* __restrict__ bits) {
    unsigned int i = blockIdx.x * 256u + threadIdx.x;   // over B*S*S = 8388608
    int pred = mask[i] != 0;
    unsigned long long b = __ballot(pred);
    if ((threadIdx.x & 63u) == 0u) bits[i >> 6] = b;
}

// ---------------- GEMM: C[M,N] = (A[M,K] * W[N,K]^T + bias) * scale ----------------
// 128x128 tile, BK=32, 4 waves (2x2), each wave 64x64 = 4x4 frags of 16x16x32 bf16 MFMA.
template <typename OutT>
__device__ inline void gemm_bt_body(const short* __restrict__ A, const short* __restrict__ W,
                                    const float* __restrict__ bias, OutT* __restrict__ C,
                                    int M, int N, int K, int rowBase, int colBase, float scale) {
    __shared__ short As[128 * 32];
    __shared__ short Bs[128 * 32];
    const int tid = threadIdx.x, lane = tid & 63, wid = tid >> 6;
    const int r15 = lane & 15, hi = lane >> 4;
    const int wr = wid >> 1, wc = wid & 1;

    f32x4 acc[4][4] = {};

    for (int kt = 0; kt < K; kt += 32) {
#pragma unroll
        for (int c = 0; c < 2; ++c) {
            int chBase = c * 256 + wid * 64;     // wave-uniform LDS base (lane*16 added by HW)
            int ch = chBase + lane;
            gload_lds16(A + (size_t)(rowBase + (ch >> 2)) * K + kt + (ch & 3) * 8, &As[chBase * 8]);
        }
#pragma unroll
        for (int c = 0; c < 2; ++c) {
            int chBase = c * 256 + wid * 64;
            int ch = chBase + lane;
            gload_lds16(W + (size_t)(colBase + (ch >> 2)) * K + kt + (ch & 3) * 8, &Bs[chBase * 8]);
        }
        __syncthreads();

        short8 aF[4], bF[4];
#pragma unroll
        for (int mi = 0; mi < 4; ++mi)
            aF[mi] = *(const short8*)&As[(wr * 64 + mi * 16 + r15) * 32 + hi * 8];
#pragma unroll
        for (int ni = 0; ni < 4; ++ni)
            bF[ni] = *(const short8*)&Bs[(wc * 64 + ni * 16 + r15) * 32 + hi * 8];
#pragma unroll
        for (int mi = 0; mi < 4; ++mi)
#pragma unroll
            for (int ni = 0; ni < 4; ++ni)
                acc[mi][ni] = __builtin_amdgcn_mfma_f32_16x16x32_bf16(aF[mi], bF[ni], acc[mi][ni], 0, 0, 0);
        __syncthreads();
    }

    // epilogue: D layout col=lane&15, row=(lane>>4)*4+reg
#pragma unroll
    for (int ni = 0; ni < 4; ++ni) {
        int col = colBase + wc * 64 + ni * 16 + r15;
        float bv = bias[col];
#pragma unroll
        for (int mi = 0; mi < 4; ++mi) {
#pragma unroll
            for (int r = 0; r < 4; ++r) {
                int row = rowBase + wr * 64 + mi * 16 + hi * 4 + r;
                float v = (acc[mi][ni][r] + bv) * scale;
                if constexpr (sizeof(OutT) == 2) C[(size_t)row * N + col] = f2bf(v);
                else                             C[(size_t)row * N + col] = v;
            }
        }
    }
}

// QKV fused: blockIdx.z selects {Wq,Wk,Wv}. Q is pre-scaled by QSCALE (log2-domain softmax).
__global__ __launch_bounds__(256, 2) void gemm_qkv_kernel(
    const short* __restrict__ A,
    const short* __restrict__ W0, const short* __restrict__ W1, const short* __restrict__ W2,
    const float* __restrict__ b0, const float* __restrict__ b1, const float* __restrict__ b2,
    short* __restrict__ O0, short* __restrict__ O1, short* __restrict__ O2) {
    const short* W = (blockIdx.z == 0) ? W0 : (blockIdx.z == 1) ? W1 : W2;
    const float* bias = (blockIdx.z == 0) ? b0 : (blockIdx.z == 1) ? b1 : b2;
    short* C = (blockIdx.z == 0) ? O0 : (blockIdx.z == 1) ? O1 : O2;
    float scale = (blockIdx.z == 0) ? QSCALE : 1.0f;
    gemm_bt_body<short>(A, W, bias, C, SM, SD, SD, blockIdx.y * 128, blockIdx.x * 128, scale);
}

__global__ __launch_bounds__(256, 2) void gemm_out_kernel(
    const short* __restrict__ A, const short* __restrict__ W,
    const float* __restrict__ bias, float* __restrict__ C) {
    gemm_bt_body<float>(A, W, bias, C, SM, SD, SD, blockIdx.y * 128, blockIdx.x * 128, 1.0f);
}

// ---------------- flash attention ----------------
// grid: (S/128, H, B); block 512 = 8 waves; wave owns 16 q rows; KV tile = 64.
// Softmax runs in log2 domain (Q pre-scaled by 0.125*log2e in the QKV GEMM).
__global__ __launch_bounds__(512, 4) void attn_kernel(
    const short* __restrict__ Q, const short* __restrict__ K, const short* __restrict__ V,
    const unsigned long long* __restrict__ mbits, short* __restrict__ O) {
    const int tid = threadIdx.x, lane = tid & 63, wid = tid >> 6;
    const int r15 = lane & 15, hi = lane >> 4;
    const int b = blockIdx.z, h = blockIdx.y;
    const int q0 = blockIdx.x * 128 + wid * 16;   // wave's first q row (within S)
    const int brow = b * SS;

    __shared__ short Ks[64 * 64];        // XOR-swizzled within 128B rows
    __shared__ short Vt[64 * 72];        // [dh][72] transposed V, +8 pad
    __shared__ short Pl[8][16 * 72];     // per-wave P round-trip, chunk-XOR swizzled
    short* pw = Pl[wid];

    // Q fragments in registers for all tiles (already scaled by QSCALE)
    short8 qF[2];
#pragma unroll
    for (int kd = 0; kd < 2; ++kd)
        qF[kd] = *(const short8*)&Q[(size_t)(brow + q0 + r15) * SD + h * SDH + kd * 32 + hi * 8];

    f32x4 o[4] = {};
    f32x4 mrun, lrun;
#pragma unroll
    for (int r = 0; r < 4; ++r) { mrun[r] = -1e30f; lrun[r] = 0.f; }

    for (int kt = 0; kt < SS; kt += 64) {
        // ---- stage K tile [64][64]: 512 chunks, 1 per thread; source-swizzled ----
        {
            int chBase = wid * 64;
            int ch = chBase + lane;             // 0..511
            int row = ch >> 3, c16 = ch & 7;
            gload_lds16(K + (size_t)(brow + kt + row) * SD + h * SDH + ((c16 ^ (row & 7)) * 8),
                        &Ks[chBase * 8]);
        }
        // ---- stage V transposed: row-pair p=tid&31, col chunk c0=(tid>>5)*4 ----
        {
            int p = tid & 31, c0 = (tid >> 5) * 4;
            const short* vs = V + (size_t)(brow + kt + 2 * p) * SD + h * SDH + c0;
            short4v va = *(const short4v*)vs;
            short4v vb = *(const short4v*)(vs + SD);
#pragma unroll
            for (int j = 0; j < 4; ++j) {
                uint32_t pk = (uint32_t)(uint16_t)va[j] | ((uint32_t)(uint16_t)vb[j] << 16);
                *(uint32_t*)&Vt[(c0 + j) * 72 + 2 * p] = pk;
            }
        }
        // mask bits: lanes 0..15 hold this wave's q-rows' 64 bits for this tile
        unsigned long long mb = 0;
        if (lane < 16) mb = mbits[(size_t)(brow + q0 + lane) * (SS / 64) + (kt >> 6)];
        __syncthreads();

        // ---- QK^T: s[kc], D row=q(hi*4+r), col=k(kc*16+r15) -- log2-domain scores ----
        f32x4 s[4] = {};
#pragma unroll
        for (int kc = 0; kc < 4; ++kc) {
            int krow = kc * 16 + r15;
#pragma unroll
            for (int kd = 0; kd < 2; ++kd) {
                short8 kF = *(const short8*)&Ks[krow * 64 + (((kd * 4 + hi) ^ (krow & 7)) * 8)];
                s[kc] = __builtin_amdgcn_mfma_f32_16x16x32_bf16(qF[kd], kF, s[kc], 0, 0, 0);
            }
        }

        // ---- mask + row max ----
        f32x4 mx;
#pragma unroll
        for (int r = 0; r < 4; ++r) {
            unsigned long long mrow = __shfl(mb, hi * 4 + r);
            unsigned lo32 = (unsigned)mrow, hi32 = (unsigned)(mrow >> 32);
            unsigned hw[4] = { lo32, lo32 >> 16, hi32, hi32 >> 16 };
            float m = -1e30f;
#pragma unroll
            for (int kc = 0; kc < 4; ++kc) {
                float v = ((hw[kc] >> r15) & 1u) ? s[kc][r] : NEGINF_MASK;
                s[kc][r] = v;
                m = fmaxf(m, v);
            }
            m = fmaxf(m, __shfl_xor(m, 1));
            m = fmaxf(m, __shfl_xor(m, 2));
            m = fmaxf(m, __shfl_xor(m, 4));
            m = fmaxf(m, __shfl_xor(m, 8));
            mx[r] = m;
        }

        // ---- defer-rescale (T13, THR=8 in log2 units): rescale only if some row's max grew ----
        bool grew = (mx[0] > mrun[0] + 8.f) || (mx[1] > mrun[1] + 8.f) ||
                    (mx[2] > mrun[2] + 8.f) || (mx[3] > mrun[3] + 8.f);
        if (__any(grew)) {
#pragma unroll
            for (int r = 0; r < 4; ++r) {
                float nm = fmaxf(mrun[r], mx[r]);
                float corr = exp2f(mrun[r] - nm);
                mrun[r] = nm;
                lrun[r] *= corr;
#pragma unroll
                for (int df = 0; df < 4; ++df) o[df][r] *= corr;
            }
        }

        // ---- exp + row sum ----
#pragma unroll
        for (int r = 0; r < 4; ++r) {
            float rs = 0.f;
#pragma unroll
            for (int kc = 0; kc < 4; ++kc) {
                float p = exp2f(s[kc][r] - mrun[r]);
                s[kc][r] = p;
                rs += p;
            }
            rs += __shfl_xor(rs, 1); rs += __shfl_xor(rs, 2);
            rs += __shfl_xor(rs, 4); rs += __shfl_xor(rs, 8);
            lrun[r] += rs;
        }

        // ---- P: D-layout -> LDS (chunk-XOR swizzled) -> A-layout, wave-private ----
#pragma unroll
        for (int kc = 0; kc < 4; ++kc)
#pragma unroll
            for (int r = 0; r < 4; ++r)
                pw[(hi * 4 + r) * 72 + ((kc ^ hi) * 16 + r15)] = f2bf(s[kc][r]);

        short8 pF[2];
#pragma unroll
        for (int kf = 0; kf < 2; ++kf) {
            int chunk = (kf * 2 + (hi >> 1)) ^ (r15 >> 2);
            pF[kf] = *(const short8*)&pw[r15 * 72 + chunk * 16 + (hi & 1) * 8];
        }

        // ---- PV: o[df] += P * V ----
#pragma unroll
        for (int df = 0; df < 4; ++df) {
#pragma unroll
            for (int kf = 0; kf < 2; ++kf) {
                short8 vF = *(const short8*)&Vt[(df * 16 + r15) * 72 + kf * 32 + hi * 8];
                o[df] = __builtin_amdgcn_mfma_f32_16x16x32_bf16(pF[kf], vF, o[df], 0, 0, 0);
            }
        }
        __syncthreads();   // protect Ks/Vt before next stage
    }

    // ---- epilogue: O = o / l, bf16 out at [b*S+q][h*64+dh] ----
#pragma unroll
    for (int r = 0; r < 4; ++r) {
        float inv = 1.0f / lrun[r];
        size_t row = (size_t)(brow + q0 + hi * 4 + r);
#pragma unroll
        for (int df = 0; df < 4; ++df)
            O[row * SD + h * SDH + df * 16 + r15] = f2bf(o[df][r] * inv);
    }
}

// ---------------- host launcher ----------------
extern "C" void kernel_launch(void* const* d_in, const int* in_sizes, int n_in,
                              void* d_out, int out_size, void* d_ws, size_t ws_size,
                              hipStream_t stream) {
    const float* x  = (const float*)d_in[0];
    const int* mask = (const int*)d_in[1];
    const float* Wq = (const float*)d_in[2];
    const float* bq = (const float*)d_in[3];
    const float* Wk = (const float*)d_in[4];
    const float* bk = (const float*)d_in[5];
    const float* Wv = (const float*)d_in[6];
    const float* bv = (const float*)d_in[7];
    const float* Wo = (const float*)d_in[8];
    const float* bo = (const float*)d_in[9];
    float* out = (float*)d_out;

    char* ws = (char*)d_ws;
    size_t off = 0;
    auto alloc = [&](size_t bytes) { void* p = ws + off; off += (bytes + 255) & ~(size_t)255; return p; };

    short* xb  = (short*)alloc((size_t)SM * SD * 2);
    short* wqb = (short*)alloc((size_t)SD * SD * 2);
    short* wkb = (short*)alloc((size_t)SD * SD * 2);
    short* wvb = (short*)alloc((size_t)SD * SD * 2);
    short* wob = (short*)alloc((size_t)SD * SD * 2);
    short* Qb  = (short*)alloc((size_t)SM * SD * 2);
    short* Kb  = (short*)alloc((size_t)SM * SD * 2);
    short* Vb  = (short*)alloc((size_t)SM * SD * 2);
    short* AOb = (short*)alloc((size_t)SM * SD * 2);
    unsigned long long* mbits = (unsigned long long*)alloc((size_t)SB * SS * (SS / 64) * 8);

    cvt_bf16_kernel<<<(SM * SD / 4 + 255) / 256, 256, 0, stream>>>(x, xb, SM * SD / 4);
    cvt_bf16_kernel<<<(SD * SD / 4 + 255) / 256, 256, 0, stream>>>(Wq, wqb, SD * SD / 4);
    cvt_bf16_kernel<<<(SD * SD / 4 + 255) / 256, 256, 0, stream>>>(Wk, wkb, SD * SD / 4);
    cvt_bf16_kernel<<<(SD * SD / 4 + 255) / 256, 256, 0, stream>>>(Wv, wvb, SD * SD / 4);
    cvt_bf16_kernel<<<(SD * SD / 4 + 255) / 256, 256, 0, stream>>>(Wo, wob, SD * SD / 4);
    pack_mask_kernel<<<SB * SS * SS / 256, 256, 0, stream>>>(mask, mbits);

    gemm_qkv_kernel<<<dim3(SD / 128, SM / 128, 3), 256, 0, stream>>>(
        xb, wqb, wkb, wvb, bq, bk, bv, Qb, Kb, Vb);

    attn_kernel<<<dim3(SS / 128, SH, SB), 512, 0, stream>>>(Qb, Kb, Vb, mbits, AOb);

    gemm_out_kernel<<<dim3(SD / 128, SM / 128), 256, 0, stream>>>(AOb, wob, bo, out);
}

// Round 3
// 168.401 us; speedup vs baseline: 1.3916x; 1.3592x over previous
//
#include <hip/hip_runtime.h>
#include <stdint.h>

// Problem constants: B=2, S=2048, D=1024, H=16, DH=64
#define SB 2
#define SS 2048
#define SD 1024
#define SH 16
#define SDH 64
#define SM (SB*SS)          // 4096 rows
#define NEGINF_MASK -1000000000.0f
// Q pre-scale: (1/sqrt(DH)) * log2(e) = 0.125 * 1.4426950408889634
#define QSCALE 0.18033688011112043f

typedef __attribute__((ext_vector_type(8))) short short8;
typedef __attribute__((ext_vector_type(4))) short short4v;
typedef __attribute__((ext_vector_type(4))) float f32x4;
typedef __attribute__((ext_vector_type(4))) float float4v;
typedef __attribute__((ext_vector_type(2))) uint32_t uint2v;

__device__ static inline short f2bf(float f) {
    uint32_t u = __float_as_uint(f);
    u += 0x7fffu + ((u >> 16) & 1u);   // RNE
    return (short)(u >> 16);
}

__device__ static inline void gload_lds16(const void* g, void* l) {
    __builtin_amdgcn_global_load_lds(
        (__attribute__((address_space(1))) void*)g,
        (__attribute__((address_space(3))) void*)l,
        16, 0, 0);
}

// ---------------- fp32 -> bf16 convert (vectorized) ----------------
__global__ void cvt_bf16_kernel(const float* __restrict__ in, short* __restrict__ out, int n4) {
    int i = blockIdx.x * 256 + threadIdx.x;
    if (i < n4) {
        float4v v = *(const float4v*)(in + (size_t)i * 4);
        short4v o;
        o[0] = f2bf(v[0]); o[1] = f2bf(v[1]); o[2] = f2bf(v[2]); o[3] = f2bf(v[3]);
        *(short4v*)(out + (size_t)i * 4) = o;
    }
}

// ---------------- mask [B,S,S] int32 -> bit-packed u64 ----------------
__global__ void pack_mask_kernel(const int* __restrict__ mask, unsigned long long* __restrict__ bits) {
    unsigned int i = blockIdx.x * 256u + threadIdx.x;   // over B*S*S = 8388608
    int pred = mask[i] != 0;
    unsigned long long b = __ballot(pred);
    if ((threadIdx.x & 63u) == 0u) bits[i >> 6] = b;
}

// ---------------- GEMM: C[M,N] = (A[M,K] * W[N,K]^T + bias) * scale ----------------
template <typename OutT>
__device__ inline void gemm_bt_body(const short* __restrict__ A, const short* __restrict__ W,
                                    const float* __restrict__ bias, OutT* __restrict__ C,
                                    int M, int N, int K, int rowBase, int colBase, float scale) {
    __shared__ short As[128 * 32];
    __shared__ short Bs[128 * 32];
    const int tid = threadIdx.x, lane = tid & 63, wid = tid >> 6;
    const int r15 = lane & 15, hi = lane >> 4;
    const int wr = wid >> 1, wc = wid & 1;

    f32x4 acc[4][4] = {};

    for (int kt = 0; kt < K; kt += 32) {
#pragma unroll
        for (int c = 0; c < 2; ++c) {
            int chBase = c * 256 + wid * 64;
            int ch = chBase + lane;
            gload_lds16(A + (size_t)(rowBase + (ch >> 2)) * K + kt + (ch & 3) * 8, &As[chBase * 8]);
        }
#pragma unroll
        for (int c = 0; c < 2; ++c) {
            int chBase = c * 256 + wid * 64;
            int ch = chBase + lane;
            gload_lds16(W + (size_t)(colBase + (ch >> 2)) * K + kt + (ch & 3) * 8, &Bs[chBase * 8]);
        }
        __syncthreads();

        short8 aF[4], bF[4];
#pragma unroll
        for (int mi = 0; mi < 4; ++mi)
            aF[mi] = *(const short8*)&As[(wr * 64 + mi * 16 + r15) * 32 + hi * 8];
#pragma unroll
        for (int ni = 0; ni < 4; ++ni)
            bF[ni] = *(const short8*)&Bs[(wc * 64 + ni * 16 + r15) * 32 + hi * 8];
#pragma unroll
        for (int mi = 0; mi < 4; ++mi)
#pragma unroll
            for (int ni = 0; ni < 4; ++ni)
                acc[mi][ni] = __builtin_amdgcn_mfma_f32_16x16x32_bf16(aF[mi], bF[ni], acc[mi][ni], 0, 0, 0);
        __syncthreads();
    }

#pragma unroll
    for (int ni = 0; ni < 4; ++ni) {
        int col = colBase + wc * 64 + ni * 16 + r15;
        float bv = bias[col];
#pragma unroll
        for (int mi = 0; mi < 4; ++mi) {
#pragma unroll
            for (int r = 0; r < 4; ++r) {
                int row = rowBase + wr * 64 + mi * 16 + hi * 4 + r;
                float v = (acc[mi][ni][r] + bv) * scale;
                if constexpr (sizeof(OutT) == 2) C[(size_t)row * N + col] = f2bf(v);
                else                             C[(size_t)row * N + col] = v;
            }
        }
    }
}

__global__ __launch_bounds__(256, 2) void gemm_qkv_kernel(
    const short* __restrict__ A,
    const short* __restrict__ W0, const short* __restrict__ W1, const short* __restrict__ W2,
    const float* __restrict__ b0, const float* __restrict__ b1, const float* __restrict__ b2,
    short* __restrict__ O0, short* __restrict__ O1, short* __restrict__ O2) {
    const short* W = (blockIdx.z == 0) ? W0 : (blockIdx.z == 1) ? W1 : W2;
    const float* bias = (blockIdx.z == 0) ? b0 : (blockIdx.z == 1) ? b1 : b2;
    short* C = (blockIdx.z == 0) ? O0 : (blockIdx.z == 1) ? O1 : O2;
    float scale = (blockIdx.z == 0) ? QSCALE : 1.0f;
    gemm_bt_body<short>(A, W, bias, C, SM, SD, SD, blockIdx.y * 128, blockIdx.x * 128, scale);
}

__global__ __launch_bounds__(256, 2) void gemm_out_kernel(
    const short* __restrict__ A, const short* __restrict__ W,
    const float* __restrict__ bias, float* __restrict__ C) {
    gemm_bt_body<float>(A, W, bias, C, SM, SD, SD, blockIdx.y * 128, blockIdx.x * 128, 1.0f);
}

// ---------------- flash attention ----------------
// grid: (S/128, H, B); block 512 = 8 waves; wave owns 16 q rows; KV tile = 64.
// Swapped QK^T (lane owns one q-row's scores), log2-domain softmax,
// double-buffered K/V with single barrier per tile (2-phase pipeline).
__global__ __launch_bounds__(512, 4) void attn_kernel(
    const short* __restrict__ Q, const short* __restrict__ K, const short* __restrict__ V,
    const unsigned long long* __restrict__ mbits, short* __restrict__ O) {
    const int tid = threadIdx.x, lane = tid & 63, wid = tid >> 6;
    const int r15 = lane & 15, hi = lane >> 4;
    const int b = blockIdx.z, h = blockIdx.y;
    const int q0 = blockIdx.x * 128 + wid * 16;
    const int brow = b * SS;

    __shared__ short Ks[2][64 * 64];     // XOR-swizzled within 128B rows, double-buffered
    __shared__ short Vt[2][64 * 72];     // [dh][72] transposed V, +8 pad, double-buffered
    __shared__ short Pl[8][16 * 64];     // per-wave P: [16 q][64 k], chunk-XOR swizzled
    char* pw = (char*)&Pl[wid][0];

    const short* Kbase = K + (size_t)brow * SD + h * SDH;
    const short* Vbase = V + (size_t)brow * SD + h * SDH;
    const unsigned long long* mrow_p = mbits + (size_t)(brow + q0 + r15) * (SS / 64);

    // Q fragments in registers (already scaled by QSCALE*... log2 domain)
    short8 qF[2];
#pragma unroll
    for (int kd = 0; kd < 2; ++kd)
        qF[kd] = *(const short8*)&Q[(size_t)(brow + q0 + r15) * SD + h * SDH + kd * 32 + hi * 8];

    f32x4 o[4] = {};
    float mrun = -1e30f, lrun = 0.f;

    const int krow_s = tid >> 3, kcol_s = tid & 7;          // K staging coords
    const int vp = tid & 31, vc0 = (tid >> 5) * 4;          // V staging coords

    // ---- prologue: stage tile 0 into buffer 0 ----
    gload_lds16(Kbase + (size_t)krow_s * SD + ((kcol_s ^ (krow_s & 7)) * 8), &Ks[0][wid * 512]);
    short4v va = *(const short4v*)(Vbase + (size_t)(2 * vp) * SD + vc0);
    short4v vb2 = *(const short4v*)(Vbase + (size_t)(2 * vp + 1) * SD + vc0);
    unsigned long long mb = mrow_p[0];
#pragma unroll
    for (int j = 0; j < 4; ++j) {
        uint32_t pk = (uint32_t)(uint16_t)va[j] | ((uint32_t)(uint16_t)vb2[j] << 16);
        *(uint32_t*)&Vt[0][(vc0 + j) * 72 + 2 * vp] = pk;
    }

    for (int t = 0; t < SS / 64; ++t) {
        __syncthreads();                    // buf[cur] ready; buf[nxt] free
        const int cur = t & 1, nxt = cur ^ 1;
        const int tn = (t < SS / 64 - 1) ? t + 1 : t;   // clamped prefetch

        // ---- issue next-tile staging (latency hides under this tile's compute) ----
        gload_lds16(Kbase + (size_t)(tn * 64 + krow_s) * SD + ((kcol_s ^ (krow_s & 7)) * 8),
                    &Ks[nxt][wid * 512]);
        va  = *(const short4v*)(Vbase + (size_t)(tn * 64 + 2 * vp) * SD + vc0);
        vb2 = *(const short4v*)(Vbase + (size_t)(tn * 64 + 2 * vp + 1) * SD + vc0);
        unsigned long long mbn = mrow_p[tn];

        // ---- QK^T swapped: s[kc] row=k(kc*16+hi*4+r), col=q(r15) ----
        f32x4 s[4] = {};
#pragma unroll
        for (int kc = 0; kc < 4; ++kc) {
            int krow = kc * 16 + r15;
#pragma unroll
            for (int kd = 0; kd < 2; ++kd) {
                short8 kF = *(const short8*)&Ks[cur][krow * 64 + (((kd * 4 + hi) ^ (krow & 7)) * 8)];
                s[kc] = __builtin_amdgcn_mfma_f32_16x16x32_bf16(kF, qF[kd], s[kc], 0, 0, 0);
            }
        }

        // ---- mask + in-register row max ----
        float mloc = -1e30f;
#pragma unroll
        for (int kc = 0; kc < 4; ++kc) {
            unsigned nib = (unsigned)(mb >> (kc * 16 + hi * 4)) & 0xFu;
#pragma unroll
            for (int r = 0; r < 4; ++r) {
                float v = (nib & (1u << r)) ? s[kc][r] : NEGINF_MASK;
                s[kc][r] = v;
                mloc = fmaxf(mloc, v);
            }
        }
        mloc = fmaxf(mloc, __shfl_xor(mloc, 16));
        mloc = fmaxf(mloc, __shfl_xor(mloc, 32));

        // ---- defer-rescale (THR=8 in log2 units) ----
        if (__any(mloc > mrun + 8.f)) {
            float nm = fmaxf(mrun, mloc);
            float corr = exp2f(mrun - nm);
            mrun = nm; lrun *= corr;
            float cr[4];
#pragma unroll
            for (int r = 0; r < 4; ++r) cr[r] = __shfl(corr, hi * 4 + r);
#pragma unroll
            for (int df = 0; df < 4; ++df)
#pragma unroll
                for (int r = 0; r < 4; ++r) o[df][r] *= cr[r];
        }

        // ---- exp + in-register row sum ----
        float rs = 0.f;
#pragma unroll
        for (int kc = 0; kc < 4; ++kc)
#pragma unroll
            for (int r = 0; r < 4; ++r) {
                float p = exp2f(s[kc][r] - mrun);
                s[kc][r] = p;
                rs += p;
            }
        rs += __shfl_xor(rs, 16);
        rs += __shfl_xor(rs, 32);
        lrun += rs;

        // ---- P pack (cvt_pk) + 4x ds_write_b64, chunk-XOR swizzled ----
#pragma unroll
        for (int kc = 0; kc < 4; ++kc) {
            uint32_t d0, d1;
            asm("v_cvt_pk_bf16_f32 %0, %1, %2" : "=v"(d0) : "v"(s[kc][0]), "v"(s[kc][1]));
            asm("v_cvt_pk_bf16_f32 %0, %1, %2" : "=v"(d1) : "v"(s[kc][2]), "v"(s[kc][3]));
            int chunk = (2 * kc + (hi >> 1)) ^ (r15 & 7);
            uint2v val = { d0, d1 };
            *(uint2v*)(pw + r15 * 128 + chunk * 16 + (hi & 1) * 8) = val;
        }

        // ---- P read back in A-layout (wave-private, DS in-order) ----
        short8 pF[2];
#pragma unroll
        for (int kf = 0; kf < 2; ++kf) {
            int chunk = (4 * kf + hi) ^ (r15 & 7);
            pF[kf] = *(const short8*)(pw + r15 * 128 + chunk * 16);
        }

        // ---- PV: o[df] += P * V ----
#pragma unroll
        for (int df = 0; df < 4; ++df) {
#pragma unroll
            for (int kf = 0; kf < 2; ++kf) {
                short8 vF = *(const short8*)&Vt[cur][(df * 16 + r15) * 72 + kf * 32 + hi * 8];
                o[df] = __builtin_amdgcn_mfma_f32_16x16x32_bf16(pF[kf], vF, o[df], 0, 0, 0);
            }
        }

        // ---- write prefetched V into Vt[nxt] (after PV reads of Vt[cur]) ----
#pragma unroll
        for (int j = 0; j < 4; ++j) {
            uint32_t pk = (uint32_t)(uint16_t)va[j] | ((uint32_t)(uint16_t)vb2[j] << 16);
            *(uint32_t*)&Vt[nxt][(vc0 + j) * 72 + 2 * vp] = pk;
        }
        mb = mbn;
    }

    // ---- epilogue: O = o / l ----
#pragma unroll
    for (int r = 0; r < 4; ++r) {
        float lq = __shfl(lrun, hi * 4 + r);
        float inv = 1.0f / lq;
        size_t row = (size_t)(brow + q0 + hi * 4 + r);
#pragma unroll
        for (int df = 0; df < 4; ++df)
            O[row * SD + h * SDH + df * 16 + r15] = f2bf(o[df][r] * inv);
    }
}

// ---------------- host launcher ----------------
extern "C" void kernel_launch(void* const* d_in, const int* in_sizes, int n_in,
                              void* d_out, int out_size, void* d_ws, size_t ws_size,
                              hipStream_t stream) {
    const float* x  = (const float*)d_in[0];
    const int* mask = (const int*)d_in[1];
    const float* Wq = (const float*)d_in[2];
    const float* bq = (const float*)d_in[3];
    const float* Wk = (const float*)d_in[4];
    const float* bk = (const float*)d_in[5];
    const float* Wv = (const float*)d_in[6];
    const float* bv = (const float*)d_in[7];
    const float* Wo = (const float*)d_in[8];
    const float* bo = (const float*)d_in[9];
    float* out = (float*)d_out;

    char* ws = (char*)d_ws;
    size_t off = 0;
    auto alloc = [&](size_t bytes) { void* p = ws + off; off += (bytes + 255) & ~(size_t)255; return p; };

    short* xb  = (short*)alloc((size_t)SM * SD * 2);
    short* wqb = (short*)alloc((size_t)SD * SD * 2);
    short* wkb = (short*)alloc((size_t)SD * SD * 2);
    short* wvb = (short*)alloc((size_t)SD * SD * 2);
    short* wob = (short*)alloc((size_t)SD * SD * 2);
    short* Qb  = (short*)alloc((size_t)SM * SD * 2);
    short* Kb  = (short*)alloc((size_t)SM * SD * 2);
    short* Vb  = (short*)alloc((size_t)SM * SD * 2);
    short* AOb = (short*)alloc((size_t)SM * SD * 2);
    unsigned long long* mbits = (unsigned long long*)alloc((size_t)SB * SS * (SS / 64) * 8);

    cvt_bf16_kernel<<<(SM * SD / 4 + 255) / 256, 256, 0, stream>>>(x, xb, SM * SD / 4);
    cvt_bf16_kernel<<<(SD * SD / 4 + 255) / 256, 256, 0, stream>>>(Wq, wqb, SD * SD / 4);
    cvt_bf16_kernel<<<(SD * SD / 4 + 255) / 256, 256, 0, stream>>>(Wk, wkb, SD * SD / 4);
    cvt_bf16_kernel<<<(SD * SD / 4 + 255) / 256, 256, 0, stream>>>(Wv, wvb, SD * SD / 4);
    cvt_bf16_kernel<<<(SD * SD / 4 + 255) / 256, 256, 0, stream>>>(Wo, wob, SD * SD / 4);
    pack_mask_kernel<<<SB * SS * SS / 256, 256, 0, stream>>>(mask, mbits);

    gemm_qkv_kernel<<<dim3(SD / 128, SM / 128, 3), 256, 0, stream>>>(
        xb, wqb, wkb, wvb, bq, bk, bv, Qb, Kb, Vb);

    attn_kernel<<<dim3(SS / 128, SH, SB), 512, 0, stream>>>(Qb, Kb, Vb, mbits, AOb);

    gemm_out_kernel<<<dim3(SD / 128, SM / 128), 256, 0, stream>>>(AOb, wob, bo, out);
}